// Round 1
// baseline (2306.623 us; speedup 1.0000x reference)
//
#include <hip/hip_runtime.h>

// EMSA: windowed multi-head self-attention, fully fused, fp32.
// One block = one 7x7 window. 4096 windows, 512 threads (8 waves).
// LDS strides are odd (53) => conflict-free for both [row][lane] and
// [lane][col] scalar access patterns.

#define WS    7
#define L     49          // WS*WS pixels per window
#define CCH   128         // channels
#define HEADS 8
#define HC    16          // channels per head
#define NHW   32          // windows per side (224/7)
#define IMG   224
#define TPB   512
#define NWAVE 8
#define STR   53          // LDS row stride (odd -> conflict-free)

__global__ __launch_bounds__(TPB, 4)
void emsa_fused(const float* __restrict__ x,
                const float* __restrict__ w_qkv,
                const float* __restrict__ b_qkv,
                const float* __restrict__ w_out,
                const float* __restrict__ b_out,
                float* __restrict__ y) {
    __shared__ float xw[CCH * STR];    // [c][p] input window
    __shared__ float qkvh[48 * STR];   // per-head: rows 0-15 q, 16-31 k, 32-47 v
    __shared__ float sc[L * STR];      // [l][m] scores -> probs
    __shared__ float outw[CCH * STR];  // [c][p] attention output (all heads)

    const int win = blockIdx.x;
    const int b   = win >> 10;         // 1024 windows per batch image
    const int wh  = (win >> 5) & 31;
    const int ww  = win & 31;

    const int tid  = threadIdx.x;
    const int wid  = tid >> 6;
    const int lane = tid & 63;

    const int h0 = wh * WS, w0 = ww * WS;
    const float* xb = x + (size_t)b * CCH * IMG * IMG;

    // ---- stage 0: load window into LDS ----
    for (int i = tid; i < CCH * L; i += TPB) {
        int c = i / L, p = i - c * L;
        int pi = p / WS, pj = p - pi * WS;
        xw[c * STR + p] = xb[((size_t)c * IMG + (h0 + pi)) * IMG + (w0 + pj)];
    }
    __syncthreads();

    const int  p   = lane;             // pixel index within window
    const bool act = (p < L);

    for (int head = 0; head < HEADS; ++head) {
        // ---- stage A: qkv for this head. wave 'wid' computes rows r0..r0+5 ----
        {
            const int r0 = wid * 6;
            float acc[6];
            const float* wrow[6];
#pragma unroll
            for (int u = 0; u < 6; ++u) {
                int r = r0 + u;
                int part = r >> 4;                       // 0=q 1=k 2=v
                int o = part * CCH + head * HC + (r & 15);
                wrow[u] = w_qkv + (size_t)o * CCH;
                acc[u] = b_qkv[o];
            }
            if (act) {
                for (int c = 0; c < CCH; c += 4) {
                    float x0 = xw[(c + 0) * STR + p];
                    float x1 = xw[(c + 1) * STR + p];
                    float x2 = xw[(c + 2) * STR + p];
                    float x3 = xw[(c + 3) * STR + p];
#pragma unroll
                    for (int u = 0; u < 6; ++u) {
                        float4 wv = *(const float4*)(wrow[u] + c);
                        acc[u] += wv.x * x0 + wv.y * x1 + wv.z * x2 + wv.w * x3;
                    }
                }
#pragma unroll
                for (int u = 0; u < 6; ++u)
                    qkvh[(r0 + u) * STR + p] = acc[u];
            }
        }
        __syncthreads();

        // ---- stage B: scores + softmax. lane = key index m; wave does rows l ----
        {
            float kreg[HC];
            const int psafe = act ? p : 0;
#pragma unroll
            for (int c = 0; c < HC; ++c)
                kreg[c] = qkvh[(16 + c) * STR + psafe];

            for (int l = wid; l < L; l += NWAVE) {
                float s = 0.f;
#pragma unroll
                for (int c = 0; c < HC; ++c)
                    s += qkvh[c * STR + l] * kreg[c];   // q broadcast * k reg
                s *= 0.25f;                              // 1/sqrt(16)
                if (!act) s = -INFINITY;
                float mx = s;
#pragma unroll
                for (int off = 32; off; off >>= 1)
                    mx = fmaxf(mx, __shfl_xor(mx, off));
                float e = act ? __expf(s - mx) : 0.f;
                float sum = e;
#pragma unroll
                for (int off = 32; off; off >>= 1)
                    sum += __shfl_xor(sum, off);
                if (act) sc[l * STR + p] = e / sum;
            }
        }
        __syncthreads();

        // ---- stage C: out = V @ probs^T. wave does v-rows {2*wid, 2*wid+1}; lane = out pixel ----
        if (act) {
            const int c0 = wid * 2;
            float a0 = 0.f, a1 = 0.f;
            for (int m = 0; m < L; ++m) {
                float pr = sc[p * STR + m];
                a0 += qkvh[(32 + c0) * STR + m] * pr;
                a1 += qkvh[(33 + c0) * STR + m] * pr;
            }
            outw[(head * HC + c0) * STR + p]     = a0;
            outw[(head * HC + c0 + 1) * STR + p] = a1;
        }
        __syncthreads();
    }

    // ---- stage D: output projection. wave 'wid' computes rows o0..o0+15 ----
    {
        const int o0 = wid * 16;
        float acc[16];
#pragma unroll
        for (int u = 0; u < 16; ++u) acc[u] = b_out[o0 + u];
        if (act) {
            for (int c = 0; c < CCH; c += 2) {
                float x0 = outw[(c + 0) * STR + p];
                float x1 = outw[(c + 1) * STR + p];
#pragma unroll
                for (int u = 0; u < 16; ++u) {
                    float2 wv = *(const float2*)(w_out + (size_t)(o0 + u) * CCH + c);
                    acc[u] += wv.x * x0 + wv.y * x1;
                }
            }
            int pi = p / WS, pj = p - pi * WS;
            float* yb = y + (size_t)b * CCH * IMG * IMG + (size_t)(h0 + pi) * IMG + (w0 + pj);
#pragma unroll
            for (int u = 0; u < 16; ++u)
                yb[(size_t)(o0 + u) * IMG * IMG] = acc[u];
        }
    }
}

extern "C" void kernel_launch(void* const* d_in, const int* in_sizes, int n_in,
                              void* d_out, int out_size, void* d_ws, size_t ws_size,
                              hipStream_t stream) {
    (void)in_sizes; (void)n_in; (void)d_ws; (void)ws_size; (void)out_size;
    const float* x     = (const float*)d_in[0];
    const float* w_qkv = (const float*)d_in[1];
    const float* b_qkv = (const float*)d_in[2];
    const float* w_out = (const float*)d_in[3];
    const float* b_out = (const float*)d_in[4];
    float* y = (float*)d_out;

    const int nwin = 4 * NHW * NHW;   // 4096 windows
    emsa_fused<<<nwin, TPB, 0, stream>>>(x, w_qkv, b_qkv, w_out, b_out, y);
}

// Round 2
// 529.575 us; speedup vs baseline: 4.3556x; 4.3556x over previous
//
#include <hip/hip_runtime.h>

// EMSA fused windowed MHSA, bf16 MFMA version.
// One block = one 7x7 window (4096 blocks), 512 threads = 8 waves.
// All GEMM-shaped work on v_mfma_f32_16x16x32_bf16 (fp32 accumulate).
//
// MFMA fragment layouts (verified, guide §3 m89):
//   A[16][32]: lane l holds A[l&15][(l>>4)*8 + j], j=0..7   (16B contiguous)
//   B[32][16]: lane l holds B[(l>>4)*8 + j][l&15]           (16B contiguous, k-major)
//   D[16][16]: lane l holds D[(l>>4)*4 + r][l&15], r=0..3

#define IMG   224
#define NPIX  (IMG*IMG)
#define CCH   128
#define WS    7
#define L     49
#define LP    64
#define HEADS 8
#define TPB   512

// LDS element strides (bf16 elements); all give 16B-aligned rows and
// row-to-row bank rotation (stride/4 mod 32 != 0).
#define XS 136   // xa: x-window / attn-out transposed [64][136]
#define QS 264   // qT: per-head 32-padded channels [64][8*32=256 (+8)]
#define KS 152   // kT: [64][144 (+8)], cols 128..143 zeroed (head-7 overread)
#define VS 72    // vm: [128][72] channel-major V
#define PS 72    // P:  [64][72] probs, per 4-wave group

typedef short s8v __attribute__((ext_vector_type(8)));
typedef short s4v __attribute__((ext_vector_type(4)));
typedef float f32x4 __attribute__((ext_vector_type(4)));

__device__ __forceinline__ short f2bf(float f) {
    unsigned int u = __float_as_uint(f);
    u += 0x7fffu + ((u >> 16) & 1u);       // round-to-nearest-even
    return (short)(u >> 16);
}

__global__ void cvt_weights(const float* __restrict__ wq,
                            const float* __restrict__ wo,
                            short* __restrict__ out) {
    int i = blockIdx.x * 256 + threadIdx.x;      // 65536 total
    if (i < 384 * CCH) out[i] = f2bf(wq[i]);
    else               out[i] = f2bf(wo[i - 384 * CCH]);
}

__global__ __launch_bounds__(TPB, 2)
void emsa_mfma(const float* __restrict__ x,
               const short* __restrict__ wq,    // bf16 [384][128]
               const short* __restrict__ wo,    // bf16 [128][128]
               const float* __restrict__ bq,
               const float* __restrict__ bo,
               float* __restrict__ y) {
    __shared__ __align__(16) short xa[LP * XS];
    __shared__ __align__(16) short qT[LP * QS];
    __shared__ __align__(16) short kT[LP * KS];
    __shared__ __align__(16) short vm[CCH * VS];
    __shared__ __align__(16) short P0[LP * PS];
    __shared__ __align__(16) short P1[LP * PS];
    __shared__ float bqs[384];
    __shared__ float bos[128];

    const int win = blockIdx.x;
    const int b  = win >> 10;
    const int wh = (win >> 5) & 31;
    const int ww = win & 31;
    const int h0 = wh * WS, w0 = ww * WS;

    const int tid  = threadIdx.x;
    const int wid  = tid >> 6;
    const int lane = tid & 63;
    const int lg   = lane >> 4;     // k-group / row-group
    const int lc   = lane & 15;     // col-in-16

    // ================= phase 0: zero pads, biases, load x window =================
    {
        unsigned int* z = (unsigned int*)qT;
        for (int i = tid; i < LP * QS / 2; i += TPB) z[i] = 0u;
        z = (unsigned int*)kT;
        for (int i = tid; i < LP * KS / 2; i += TPB) z[i] = 0u;
        z = (unsigned int*)(xa + L * XS);             // rows 49..63
        for (int i = tid; i < (LP - L) * XS / 2; i += TPB) z[i] = 0u;
        if (tid < 384) bqs[tid] = bq[tid];
        else           bos[tid - 384] = bo[tid - 384];
        const float* xb = x + (size_t)b * CCH * NPIX;
        for (int i = tid; i < CCH * L; i += TPB) {
            int c = i / L, p = i - c * L;
            int pi = p / WS, pj = p - pi * WS;
            float v = xb[(size_t)c * NPIX + (size_t)(h0 + pi) * IMG + (w0 + pj)];
            xa[p * XS + c] = f2bf(v);
        }
    }
    __syncthreads();

    // ================= phase 1: QKV = Wq @ X  (M=384,N=64,K=128) =================
    {
        f32x4 acc[3][4];
#pragma unroll
        for (int m = 0; m < 3; ++m) {
            int o0 = wid * 48 + m * 16;
#pragma unroll
            for (int t = 0; t < 4; ++t)
#pragma unroll
                for (int r = 0; r < 4; ++r)
                    acc[m][t][r] = bqs[o0 + 4 * lg + r];
        }
#pragma unroll
        for (int s = 0; s < 4; ++s) {
            s8v af[3], bf[4];
#pragma unroll
            for (int m = 0; m < 3; ++m) {
                int o = wid * 48 + m * 16 + lc;
                af[m] = *(const s8v*)(wq + o * CCH + s * 32 + lg * 8);
            }
#pragma unroll
            for (int t = 0; t < 4; ++t)
                bf[t] = *(const s8v*)(&xa[(t * 16 + lc) * XS + s * 32 + lg * 8]);
#pragma unroll
            for (int m = 0; m < 3; ++m)
#pragma unroll
                for (int t = 0; t < 4; ++t)
                    acc[m][t] = __builtin_amdgcn_mfma_f32_16x16x32_bf16(
                        af[m], bf[t], acc[m][t], 0, 0, 0);
        }
        // epilogue: scatter into qT (head-padded), kT, vm
#pragma unroll
        for (int m = 0; m < 3; ++m) {
            int o0   = wid * 48 + m * 16;
            int part = o0 >> 7;          // 0=q 1=k 2=v (tiles never straddle)
            int chb  = o0 & 127;         // 16-aligned channel base within part
#pragma unroll
            for (int t = 0; t < 4; ++t) {
                int p = t * 16 + lc;
                if (part < 2) {
                    s4v v;
#pragma unroll
                    for (int r = 0; r < 4; ++r) v[r] = f2bf(acc[m][t][r]);
                    short* dst = (part == 0)
                        ? &qT[p * QS + (chb >> 4) * 32 + 4 * lg]
                        : &kT[p * KS + chb + 4 * lg];
                    *(s4v*)dst = v;
                } else {
#pragma unroll
                    for (int r = 0; r < 4; ++r)
                        vm[(chb + 4 * lg + r) * VS + p] = f2bf(acc[m][t][r]);
                }
            }
        }
    }
    __syncthreads();

    // ================= phase 2: attention, 2 heads per iter, no barriers ========
    const int w4 = wid & 3;
    const int l0 = w4 * 16;
    short* Pb = (wid >> 2) ? P1 : P0;
    for (int it = 0; it < 4; ++it) {
        const int h = it * 2 + (wid >> 2);
        // ---- scores: D[l][m] = Q^T K (K=32 step; upper 16 ch of A are zeros)
        f32x4 sc[4];
        {
            s8v aq = *(const s8v*)(&qT[(l0 + lc) * QS + h * 32 + lg * 8]);
            f32x4 zero = {0.f, 0.f, 0.f, 0.f};
#pragma unroll
            for (int t = 0; t < 4; ++t) {
                s8v bk = *(const s8v*)(&kT[(t * 16 + lc) * KS + h * 16 + lg * 8]);
                sc[t] = __builtin_amdgcn_mfma_f32_16x16x32_bf16(aq, bk, zero, 0, 0, 0);
            }
        }
        // ---- softmax over m (rows l0+4lg+r), scale 1/sqrt(16)=0.25
#pragma unroll
        for (int r = 0; r < 4; ++r) {
            float v0 = sc[0][r] * 0.25f, v1 = sc[1][r] * 0.25f;
            float v2 = sc[2][r] * 0.25f, v3 = sc[3][r] * 0.25f;
            bool ok3 = (lc == 0);                       // m=48+lc valid only lc==0
            float mx = fmaxf(fmaxf(v0, v1), fmaxf(v2, ok3 ? v3 : -1e30f));
#pragma unroll
            for (int off = 1; off < 16; off <<= 1) mx = fmaxf(mx, __shfl_xor(mx, off));
            float e0 = __expf(v0 - mx), e1 = __expf(v1 - mx), e2 = __expf(v2 - mx);
            float e3 = ok3 ? __expf(v3 - mx) : 0.f;
            float sum = e0 + e1 + e2 + e3;
#pragma unroll
            for (int off = 1; off < 16; off <<= 1) sum += __shfl_xor(sum, off);
            float inv = 1.f / sum;
            int row = (l0 + 4 * lg + r) * PS;
            Pb[row + 0  + lc] = f2bf(e0 * inv);
            Pb[row + 16 + lc] = f2bf(e1 * inv);
            Pb[row + 32 + lc] = f2bf(e2 * inv);
            Pb[row + 48 + lc] = f2bf(e3 * inv);
        }
        // ---- PV: out^T[l][c] = P @ V^T  (wave reads only its own P rows)
        f32x4 ao = {0.f, 0.f, 0.f, 0.f};
#pragma unroll
        for (int s = 0; s < 2; ++s) {
            s8v ap = *(const s8v*)(&Pb[(l0 + lc) * PS + s * 32 + lg * 8]);
            s8v bv = *(const s8v*)(&vm[(h * 16 + lc) * VS + s * 32 + lg * 8]);
            ao = __builtin_amdgcn_mfma_f32_16x16x32_bf16(ap, bv, ao, 0, 0, 0);
        }
#pragma unroll
        for (int r = 0; r < 4; ++r)
            xa[(l0 + 4 * lg + r) * XS + h * 16 + lc] = f2bf(ao[r]);
    }
    __syncthreads();

    // ================= phase 3: Y = Wo @ A + bo  (M=128,N=64,K=128) =============
    {
        int o0 = wid * 16;
        f32x4 acc[4];
#pragma unroll
        for (int t = 0; t < 4; ++t)
#pragma unroll
            for (int r = 0; r < 4; ++r)
                acc[t][r] = bos[o0 + 4 * lg + r];
#pragma unroll
        for (int s = 0; s < 4; ++s) {
            s8v af = *(const s8v*)(wo + (o0 + lc) * CCH + s * 32 + lg * 8);
#pragma unroll
            for (int t = 0; t < 4; ++t) {
                s8v bf = *(const s8v*)(&xa[(t * 16 + lc) * XS + s * 32 + lg * 8]);
                acc[t] = __builtin_amdgcn_mfma_f32_16x16x32_bf16(af, bf, acc[t], 0, 0, 0);
            }
        }
        float* yb = y + (size_t)b * CCH * NPIX;
#pragma unroll
        for (int t = 0; t < 4; ++t) {
            int p = t * 16 + lc;
            if (p < L) {
                int pi = p / WS, pj = p - pi * WS;
                float* dst = yb + (size_t)(o0 + 4 * lg) * NPIX
                               + (size_t)(h0 + pi) * IMG + (w0 + pj);
#pragma unroll
                for (int r = 0; r < 4; ++r)
                    dst[(size_t)r * NPIX] = acc[t][r];
            }
        }
    }
}

extern "C" void kernel_launch(void* const* d_in, const int* in_sizes, int n_in,
                              void* d_out, int out_size, void* d_ws, size_t ws_size,
                              hipStream_t stream) {
    (void)in_sizes; (void)n_in; (void)out_size; (void)ws_size;
    const float* x     = (const float*)d_in[0];
    const float* w_qkv = (const float*)d_in[1];
    const float* b_qkv = (const float*)d_in[2];
    const float* w_out = (const float*)d_in[3];
    const float* b_out = (const float*)d_in[4];
    float* y = (float*)d_out;
    short* wbf = (short*)d_ws;                 // 65536 bf16 = 131072 B

    cvt_weights<<<256, 256, 0, stream>>>(w_qkv, w_out, wbf);
    emsa_mfma<<<4096, TPB, 0, stream>>>(x, wbf, wbf + 384 * CCH,
                                        b_qkv, b_out, y);
}

// Round 3
// 362.064 us; speedup vs baseline: 6.3708x; 1.4627x over previous
//
#include <hip/hip_runtime.h>

// EMSA fused windowed MHSA, bf16 MFMA, occupancy-optimized.
// One block = one 7x7 window (4096 blocks), 512 threads = 8 waves.
// LDS 74.7 KB -> 2 blocks/CU. Zero barriers inside the attention loop.
//
// MFMA 16x16x32 fragment layouts (verified, guide §3 m89):
//   A[16][32]: lane l holds A[l&15][(l>>4)*8 + j], j=0..7
//   B[32][16]: lane l holds B[(l>>4)*8 + j][l&15]
//   D[16][16]: lane l holds D[(l>>4)*4 + r][l&15], r=0..3
//
// Scores trick: K=32 MFMA over a 2-head channel span; A-frag upper/lower
// 16 k-lanes zeroed in registers selects head h / h+1. One q load + one
// set of B(k) fragments serves both heads.
// Buffer reuse: P0/P1 alias xa (dead after phase 1); attention output
// overwrites qT in place (head h's q cols dead after its own scores;
// each wave touches only its own 16 rows).

#define IMG   224
#define NPIX  (IMG*IMG)
#define CCH   128
#define WS    7
#define L     49
#define LP    64
#define TPB   512

// LDS element strides (bf16). All rows 16B-aligned; row-to-row bank
// rotation keeps ds_read conflicts <= 2-way (free, m136).
#define XS 152   // xa [64][152]: 304B/row, 76dw = 12 mod 32 -> 2-way
#define QS 136   // qT [64][136]: 272B/row, 68dw = 4 mod 32  -> 2-way
#define KS 136   // kT [64][136]
#define VS 72    // vm [128][72]: 144B/row, 36dw = 4 mod 32  -> 2-way
#define PS 72    // P  [64][72] x2, aliased on xa (2*9216B = 18432 <= 19456)

typedef short s8v __attribute__((ext_vector_type(8)));
typedef short s4v __attribute__((ext_vector_type(4)));
typedef float f32x4 __attribute__((ext_vector_type(4)));

__device__ __forceinline__ short f2bf(float f) {
    unsigned int u = __float_as_uint(f);
    u += 0x7fffu + ((u >> 16) & 1u);       // round-to-nearest-even
    return (short)(u >> 16);
}

__global__ void cvt_weights(const float* __restrict__ wq,
                            const float* __restrict__ wo,
                            short* __restrict__ out) {
    int i = blockIdx.x * 256 + threadIdx.x;      // 65536 total
    if (i < 384 * CCH) {
        float s = (i < CCH * CCH) ? 0.25f : 1.f; // fold 1/sqrt(hc) into Wq
        out[i] = f2bf(wq[i] * s);
    } else {
        out[i] = f2bf(wo[i - 384 * CCH]);
    }
}

__global__ __launch_bounds__(TPB, 4)
void emsa_mfma(const float* __restrict__ x,
               const short* __restrict__ wq,    // bf16 [384][128], q rows pre-scaled
               const short* __restrict__ wo,    // bf16 [128][128]
               const float* __restrict__ bq,
               const float* __restrict__ bo,
               float* __restrict__ y) {
    __shared__ __align__(16) short xa[LP * XS];  // x window; later P0/P1
    __shared__ __align__(16) short qT[LP * QS];  // q (scaled); later attn-out
    __shared__ __align__(16) short kT[LP * KS];  // k [pixel][ch]
    __shared__ __align__(16) short vm[CCH * VS]; // v [ch][pixel]
    __shared__ float bqs[384];
    __shared__ float bos[CCH];

    const int bid = blockIdx.x;
    const int win = ((bid & 7) << 9) | (bid >> 3);   // XCD-chunked swizzle (4096%8==0)
    const int b  = win >> 10;
    const int wh = (win >> 5) & 31;
    const int ww = win & 31;
    const int h0 = wh * WS, w0 = ww * WS;

    const int tid  = threadIdx.x;
    const int wid  = tid >> 6;
    const int lane = tid & 63;
    const int lg   = lane >> 4;
    const int lc   = lane & 15;

    // ================= phase 0: zero pad rows, biases, load x window ==========
    {
        unsigned int* z = (unsigned int*)(xa + L * XS);       // rows 49..63
        for (int i = tid; i < (LP - L) * XS / 2; i += TPB) z[i] = 0u;
        if (tid < 384) bqs[tid] = bq[tid] * ((tid < CCH) ? 0.25f : 1.f);
        else           bos[tid - 384] = bo[tid - 384];
        const float* xb = x + (size_t)b * CCH * NPIX;
        for (int i = tid; i < CCH * L; i += TPB) {
            int c = i / L, p = i - c * L;
            int pi = p / WS, pj = p - pi * WS;
            xa[p * XS + c] =
                f2bf(xb[(size_t)c * NPIX + (size_t)(h0 + pi) * IMG + (w0 + pj)]);
        }
    }
    __syncthreads();

    // ================= phase 1: QKV = Wq @ X  (M=384,N=64,K=128) ==============
    {
        f32x4 acc[3][4];
#pragma unroll
        for (int m = 0; m < 3; ++m) {
            int o0 = wid * 48 + m * 16;
#pragma unroll
            for (int t = 0; t < 4; ++t)
#pragma unroll
                for (int r = 0; r < 4; ++r)
                    acc[m][t][r] = bqs[o0 + 4 * lg + r];
        }
#pragma unroll
        for (int s = 0; s < 4; ++s) {
            s8v af[3], bf[4];
#pragma unroll
            for (int m = 0; m < 3; ++m) {
                int o = wid * 48 + m * 16 + lc;
                af[m] = *(const s8v*)(wq + o * CCH + s * 32 + lg * 8);
            }
#pragma unroll
            for (int t = 0; t < 4; ++t)
                bf[t] = *(const s8v*)(&xa[(t * 16 + lc) * XS + s * 32 + lg * 8]);
#pragma unroll
            for (int m = 0; m < 3; ++m)
#pragma unroll
                for (int t = 0; t < 4; ++t)
                    acc[m][t] = __builtin_amdgcn_mfma_f32_16x16x32_bf16(
                        af[m], bf[t], acc[m][t], 0, 0, 0);
        }
        // epilogue: scatter into qT / kT / vm
#pragma unroll
        for (int m = 0; m < 3; ++m) {
            int o0   = wid * 48 + m * 16;
            int part = o0 >> 7;              // 0=q 1=k 2=v
            int chb  = o0 & 127;
#pragma unroll
            for (int t = 0; t < 4; ++t) {
                int p = t * 16 + lc;
                if (part < 2) {
                    s4v v;
#pragma unroll
                    for (int r = 0; r < 4; ++r) v[r] = f2bf(acc[m][t][r]);
                    short* dst = (part == 0) ? &qT[p * QS + chb + 4 * lg]
                                             : &kT[p * KS + chb + 4 * lg];
                    *(s4v*)dst = v;
                } else {
#pragma unroll
                    for (int r = 0; r < 4; ++r)
                        vm[(chb + 4 * lg + r) * VS + p] = f2bf(acc[m][t][r]);
                }
            }
        }
    }
    __syncthreads();

    // ================= phase 2: attention, head pairs, zero barriers ==========
    {
        const int g  = wid >> 2;          // group 0: heads 0..3, group 1: 4..7
        const int w4 = wid & 3;
        const int l0 = w4 * 16;           // this wave's 16 query rows
        short* Pb = xa + g * (LP * PS);   // per-group P buffer (aliases xa)

        for (int pr = 0; pr < 2; ++pr) {
            const int hb = g * 4 + pr * 2;        // head pair (hb, hb+1)
            // one 16B q load spans both heads' channels
            s8v qv = *(const s8v*)(&qT[(l0 + lc) * QS + hb * 16 + lg * 8]);
            s8v z8 = {};
            s8v aqA, aqB;
            if (lg < 2) { aqA = qv; aqB = z8; }
            else        { aqA = z8; aqB = qv; }
            f32x4 zf = {0.f, 0.f, 0.f, 0.f};
            f32x4 sA[4], sB[4];
#pragma unroll
            for (int t = 0; t < 4; ++t) {
                s8v bk = *(const s8v*)(&kT[(t * 16 + lc) * KS + hb * 16 + lg * 8]);
                sA[t] = __builtin_amdgcn_mfma_f32_16x16x32_bf16(aqA, bk, zf, 0, 0, 0);
                sB[t] = __builtin_amdgcn_mfma_f32_16x16x32_bf16(aqB, bk, zf, 0, 0, 0);
            }
#pragma unroll
            for (int e = 0; e < 2; ++e) {
                const int h = hb + e;
                f32x4* sc = e ? sB : sA;
                // softmax over m for rows l0+4lg+r (scale pre-folded into Wq)
#pragma unroll
                for (int r = 0; r < 4; ++r) {
                    float v0 = sc[0][r], v1 = sc[1][r], v2 = sc[2][r], v3 = sc[3][r];
                    bool ok3 = (lc == 0);              // m=48 only valid col in tile 3
                    float mx = fmaxf(fmaxf(v0, v1), fmaxf(v2, ok3 ? v3 : -1e30f));
#pragma unroll
                    for (int off = 1; off < 16; off <<= 1)
                        mx = fmaxf(mx, __shfl_xor(mx, off));
                    float e0 = __expf(v0 - mx), e1 = __expf(v1 - mx);
                    float e2 = __expf(v2 - mx);
                    float e3 = ok3 ? __expf(v3 - mx) : 0.f;
                    float sum = e0 + e1 + e2 + e3;
#pragma unroll
                    for (int off = 1; off < 16; off <<= 1)
                        sum += __shfl_xor(sum, off);
                    float inv = 1.f / sum;
                    int row = (l0 + 4 * lg + r) * PS;
                    Pb[row + 0  + lc] = f2bf(e0 * inv);
                    Pb[row + 16 + lc] = f2bf(e1 * inv);
                    Pb[row + 32 + lc] = f2bf(e2 * inv);
                    Pb[row + 48 + lc] = f2bf(e3 * inv);
                }
                // PV: out[l][c] = sum_m P[l][m] V[c][m]; write into qT in place
                f32x4 ao = {0.f, 0.f, 0.f, 0.f};
#pragma unroll
                for (int s = 0; s < 2; ++s) {
                    s8v ap = *(const s8v*)(&Pb[(l0 + lc) * PS + s * 32 + lg * 8]);
                    s8v bv = *(const s8v*)(&vm[(h * 16 + lc) * VS + s * 32 + lg * 8]);
                    ao = __builtin_amdgcn_mfma_f32_16x16x32_bf16(ap, bv, ao, 0, 0, 0);
                }
#pragma unroll
                for (int r = 0; r < 4; ++r)
                    qT[(l0 + 4 * lg + r) * QS + h * 16 + lc] = f2bf(ao[r]);
            }
        }
    }
    __syncthreads();

    // ================= phase 3: Y = Wo @ A + bo  (M=128,N=64,K=128) ===========
    {
        int o0 = wid * 16;
        f32x4 acc[4];
#pragma unroll
        for (int t = 0; t < 4; ++t)
#pragma unroll
            for (int r = 0; r < 4; ++r)
                acc[t][r] = bos[o0 + 4 * lg + r];
#pragma unroll
        for (int s = 0; s < 4; ++s) {
            s8v af = *(const s8v*)(wo + (o0 + lc) * CCH + s * 32 + lg * 8);
#pragma unroll
            for (int t = 0; t < 4; ++t) {
                s8v bf = *(const s8v*)(&qT[(t * 16 + lc) * QS + s * 32 + lg * 8]);
                acc[t] = __builtin_amdgcn_mfma_f32_16x16x32_bf16(af, bf, acc[t], 0, 0, 0);
            }
        }
        float* yb = y + (size_t)b * CCH * NPIX;
#pragma unroll
        for (int t = 0; t < 4; ++t) {
            int p = t * 16 + lc;
            if (p < L) {
                int pi = p / WS, pj = p - pi * WS;
                float* dst = yb + (size_t)(o0 + 4 * lg) * NPIX
                               + (size_t)(h0 + pi) * IMG + (w0 + pj);
#pragma unroll
                for (int r = 0; r < 4; ++r)
                    dst[(size_t)r * NPIX] = acc[t][r];
            }
        }
    }
}

extern "C" void kernel_launch(void* const* d_in, const int* in_sizes, int n_in,
                              void* d_out, int out_size, void* d_ws, size_t ws_size,
                              hipStream_t stream) {
    (void)in_sizes; (void)n_in; (void)out_size; (void)ws_size;
    const float* x     = (const float*)d_in[0];
    const float* w_qkv = (const float*)d_in[1];
    const float* b_qkv = (const float*)d_in[2];
    const float* w_out = (const float*)d_in[3];
    const float* b_out = (const float*)d_in[4];
    float* y = (float*)d_out;
    short* wbf = (short*)d_ws;                 // 65536 bf16 = 131072 B

    cvt_weights<<<256, 256, 0, stream>>>(w_qkv, w_out, wbf);
    emsa_mfma<<<4096, TPB, 0, stream>>>(x, wbf, wbf + 384 * CCH,
                                        b_qkv, b_out, y);
}

// Round 4
// 283.449 us; speedup vs baseline: 8.1377x; 1.2774x over previous
//
#include <hip/hip_runtime.h>
#include <hip/hip_bf16.h>

// EMSA fused windowed MHSA, bf16 MFMA, swapped-scores softmax.
// One block = one 7x7 window (4096 blocks), 512 threads = 8 waves.
// LDS 74.75 KB -> 2 blocks/CU. Zero barriers inside the attention loop.
//
// MFMA 16x16x32 fragment layouts (verified, guide §3 m89):
//   A[16][32]: lane l holds A[l&15][(l>>4)*8 + j], j=0..7
//   B[32][16]: lane l holds B[(l>>4)*8 + j][l&15]
//   D[16][16]: lane l holds D[(l>>4)*4 + r][l&15], r=0..3
//
// Scores computed TRANSPOSED: D[m][l] = (K^T)(Q) so each lane holds all
// 64 m-scores of one query pixel l -> softmax = in-lane adds + 2 shfl_xor,
// no max-subtract needed (|s| <= ~0.3 by construction).

#define IMG   224
#define NPIX  (IMG*IMG)
#define CCH   128
#define WS    7
#define L     49
#define LP    64
#define TPB   512

#define XS 152   // xa [64][152] x-window; later 2x P buffers (aliased)
#define QS 136   // qT [64][136] q k-major; later attn-out (phase-3 B operand)
#define KS 136   // kT [64][136] k k-major
#define VS 72    // vm [128][72] v channel-major
#define PS 72    // P  [64][72] per head-group, aliased on xa

typedef short s8v __attribute__((ext_vector_type(8)));
typedef float f32x4 __attribute__((ext_vector_type(4)));

__device__ __forceinline__ short f2bf(float f) {
    unsigned int u = __float_as_uint(f);
    u += 0x7fffu + ((u >> 16) & 1u);       // RNE
    return (short)(u >> 16);
}

__device__ __forceinline__ unsigned int pk2(float a, float b) {
    __hip_bfloat162 h = __float22bfloat162_rn(make_float2(a, b));
    unsigned int u;
    __builtin_memcpy(&u, &h, 4);
    return u;
}

__global__ void cvt_weights(const float* __restrict__ wq,
                            const float* __restrict__ wo,
                            short* __restrict__ out) {
    int i = blockIdx.x * 256 + threadIdx.x;      // 65536 total
    if (i < 384 * CCH) {
        float s = (i < CCH * CCH) ? 0.25f : 1.f; // fold 1/sqrt(hc) into Wq
        out[i] = f2bf(wq[i] * s);
    } else {
        out[i] = f2bf(wo[i - 384 * CCH]);
    }
}

__global__ __launch_bounds__(TPB, 4)
void emsa_mfma(const float* __restrict__ x,
               const short* __restrict__ wq,    // bf16 [384][128], q pre-scaled
               const short* __restrict__ wo,    // bf16 [128][128]
               const float* __restrict__ bq,
               const float* __restrict__ bo,
               float* __restrict__ y) {
    __shared__ __align__(16) short xa[LP * XS];
    __shared__ __align__(16) short qT[LP * QS];
    __shared__ __align__(16) short kT[LP * KS];
    __shared__ __align__(16) short vm[CCH * VS];
    __shared__ float bqs[384];
    __shared__ float bos[CCH];

    const int bid = blockIdx.x;
    const int win = ((bid & 7) << 9) | (bid >> 3);   // XCD-chunked swizzle
    const int b  = win >> 10;
    const int wh = (win >> 5) & 31;
    const int ww = win & 31;
    const int h0 = wh * WS, w0 = ww * WS;

    const int tid  = threadIdx.x;
    const int wid  = tid >> 6;
    const int lane = tid & 63;
    const int lg   = lane >> 4;
    const int lc   = lane & 15;

    // -------- prefetch phase-1 weight fragments for s=0,1 (hidden by phase 0)
    s8v af01[3][2];
#pragma unroll
    for (int m = 0; m < 3; ++m) {
        int o = wid * 48 + m * 16 + lc;
#pragma unroll
        for (int s = 0; s < 2; ++s)
            af01[m][s] = *(const s8v*)(wq + o * CCH + s * 32 + lg * 8);
    }

    // ================= phase 0: biases + x window (packed, pad rows zeroed)
    {
        if (tid < 384) bqs[tid] = bq[tid] * ((tid < CCH) ? 0.25f : 1.f);
        else           bos[tid - 384] = bo[tid - 384];
        const int p  = lane;          // pixel row of xa
        const int cg = wid;           // channel-pair group 0..7
        if (p < L) {
            int pi = p / 7, pj = p - pi * 7;
            const float* src = x + (size_t)b * CCH * NPIX + (size_t)(2 * cg) * NPIX
                             + (size_t)(h0 + pi) * IMG + (w0 + pj);
#pragma unroll
            for (int j = 0; j < 8; ++j) {
                float a  = src[(size_t)(16 * j) * NPIX];
                float c2 = src[(size_t)(16 * j) * NPIX + NPIX];
                *(unsigned int*)&xa[p * XS + 2 * cg + 16 * j] = pk2(a, c2);
            }
        } else {
#pragma unroll
            for (int j = 0; j < 8; ++j)
                *(unsigned int*)&xa[p * XS + 2 * cg + 16 * j] = 0u;
        }
    }
    __syncthreads();

    // ================= phase 1: QKV = Wq @ X  (M=384,N=64,K=128) ==============
    {
        f32x4 acc[3][4];
#pragma unroll
        for (int m = 0; m < 3; ++m) {
            int o0 = wid * 48 + m * 16;
#pragma unroll
            for (int t = 0; t < 4; ++t)
#pragma unroll
                for (int r = 0; r < 4; ++r)
                    acc[m][t][r] = bqs[o0 + 4 * lg + r];
        }
        __builtin_amdgcn_s_setprio(1);
#pragma unroll
        for (int s = 0; s < 4; ++s) {
            s8v af[3], bf[4];
#pragma unroll
            for (int m = 0; m < 3; ++m) {
                if (s < 2) af[m] = af01[m][s];
                else {
                    int o = wid * 48 + m * 16 + lc;
                    af[m] = *(const s8v*)(wq + o * CCH + s * 32 + lg * 8);
                }
            }
#pragma unroll
            for (int t = 0; t < 4; ++t)
                bf[t] = *(const s8v*)(&xa[(t * 16 + lc) * XS + s * 32 + lg * 8]);
#pragma unroll
            for (int m = 0; m < 3; ++m)
#pragma unroll
                for (int t = 0; t < 4; ++t)
                    acc[m][t] = __builtin_amdgcn_mfma_f32_16x16x32_bf16(
                        af[m], bf[t], acc[m][t], 0, 0, 0);
        }
        __builtin_amdgcn_s_setprio(0);
        // epilogue: scatter into qT / kT / vm
#pragma unroll
        for (int m = 0; m < 3; ++m) {
            int o0   = wid * 48 + m * 16;
            int part = o0 >> 7;              // 0=q 1=k 2=v
            int chb  = o0 & 127;
#pragma unroll
            for (int t = 0; t < 4; ++t) {
                int p = t * 16 + lc;
                if (part < 2) {
                    uint2 w;
                    w.x = pk2(acc[m][t][0], acc[m][t][1]);
                    w.y = pk2(acc[m][t][2], acc[m][t][3]);
                    short* dst = (part == 0) ? &qT[p * QS + chb + 4 * lg]
                                             : &kT[p * KS + chb + 4 * lg];
                    *(uint2*)dst = w;
                } else {
#pragma unroll
                    for (int r = 0; r < 4; ++r)
                        vm[(chb + 4 * lg + r) * VS + p] = f2bf(acc[m][t][r]);
                }
            }
        }
    }
    __syncthreads();

    // ================= phase 2: attention, head pairs, zero barriers ==========
    {
        const int g  = wid >> 2;          // head group: 0 -> heads 0-3, 1 -> 4-7
        const int w4 = wid & 3;
        const int l0 = w4 * 16;           // this wave's 16 query pixels
        short* Pb = xa + g * (LP * PS);   // per-group P (aliases dead xa)
        const int rowP = (l0 + lc) * PS;

        for (int pr = 0; pr < 2; ++pr) {
            const int hb = g * 4 + pr * 2;        // head pair (hb, hb+1)
            // q as B-operand: col = own pixel l0+lc, k = 32 channels of the pair
            s8v qv = *(const s8v*)(&qT[(l0 + lc) * QS + hb * 16 + lg * 8]);
            s8v z8 = {};
            s8v bqA = (lg < 2) ? qv : z8;         // head hb   (ch 0..15 of span)
            s8v bqB = (lg < 2) ? z8 : qv;         // head hb+1 (ch 16..31)
            f32x4 zf = {0.f, 0.f, 0.f, 0.f};
            f32x4 sA[4], sB[4];
            __builtin_amdgcn_s_setprio(1);
#pragma unroll
            for (int t = 0; t < 4; ++t) {
                s8v ak = *(const s8v*)(&kT[(t * 16 + lc) * KS + hb * 16 + lg * 8]);
                sA[t] = __builtin_amdgcn_mfma_f32_16x16x32_bf16(ak, bqA, zf, 0, 0, 0);
                sB[t] = __builtin_amdgcn_mfma_f32_16x16x32_bf16(ak, bqB, zf, 0, 0, 0);
            }
            __builtin_amdgcn_s_setprio(0);
#pragma unroll
            for (int e = 0; e < 2; ++e) {
                const int h = hb + e;
                f32x4* sc = e ? sB : sA;
                // softmax over m for pixel l=l0+lc: lane holds m = 16t+4lg+r
                float p4[4][4];
                float sum = 0.f;
#pragma unroll
                for (int t = 0; t < 3; ++t)
#pragma unroll
                    for (int r = 0; r < 4; ++r) {
                        float ev = __expf(sc[t][r]);
                        p4[t][r] = ev; sum += ev;
                    }
                {   // tile 3: only m=48 valid (lg==0, r==0)
                    float ev = (lg == 0) ? __expf(sc[3][0]) : 0.f;
                    p4[3][0] = ev; p4[3][1] = 0.f; p4[3][2] = 0.f; p4[3][3] = 0.f;
                    sum += ev;
                }
                sum += __shfl_xor(sum, 16);
                sum += __shfl_xor(sum, 32);
                float inv = __fdividef(1.f, sum);
                // P row l: packed writes, cols m = 16t+4lg..+3
#pragma unroll
                for (int t = 0; t < 4; ++t) {
                    uint2 w;
                    w.x = pk2(p4[t][0] * inv, p4[t][1] * inv);
                    w.y = pk2(p4[t][2] * inv, p4[t][3] * inv);
                    *(uint2*)&Pb[rowP + 16 * t + 4 * lg] = w;
                }
                // PV: out[l][c], A = P[l][m] (own row), B = V[m][c] from vm
                f32x4 ao = {0.f, 0.f, 0.f, 0.f};
                __builtin_amdgcn_s_setprio(1);
#pragma unroll
                for (int s = 0; s < 2; ++s) {
                    s8v ap = *(const s8v*)(&Pb[rowP + s * 32 + lg * 8]);
                    s8v av = *(const s8v*)(&vm[(h * 16 + lc) * VS + s * 32 + lg * 8]);
                    ao = __builtin_amdgcn_mfma_f32_16x16x32_bf16(ap, av, ao, 0, 0, 0);
                }
                __builtin_amdgcn_s_setprio(0);
#pragma unroll
                for (int r = 0; r < 4; ++r)
                    qT[(l0 + 4 * lg + r) * QS + h * 16 + lc] = f2bf(ao[r]);
            }
        }
    }

    // -------- prefetch phase-3 weight fragments (hidden by phase-2 tail)
    const int o0 = wid * 16;
    s8v wof[4];
#pragma unroll
    for (int s = 0; s < 4; ++s)
        wof[s] = *(const s8v*)(wo + (o0 + lc) * CCH + s * 32 + lg * 8);
    __syncthreads();

    // ================= phase 3: Y = Wo @ A + bo  (M=128,N=64,K=128) ===========
    {
        f32x4 acc[4];
#pragma unroll
        for (int t = 0; t < 4; ++t)
#pragma unroll
            for (int r = 0; r < 4; ++r)
                acc[t][r] = bos[o0 + 4 * lg + r];
        __builtin_amdgcn_s_setprio(1);
#pragma unroll
        for (int s = 0; s < 4; ++s) {
#pragma unroll
            for (int t = 0; t < 4; ++t) {
                s8v bf = *(const s8v*)(&qT[(t * 16 + lc) * QS + s * 32 + lg * 8]);
                acc[t] = __builtin_amdgcn_mfma_f32_16x16x32_bf16(wof[s], bf, acc[t], 0, 0, 0);
            }
        }
        __builtin_amdgcn_s_setprio(0);
        float* yb = y + (size_t)b * CCH * NPIX;
#pragma unroll
        for (int t = 0; t < 4; ++t) {
            int p = t * 16 + lc;
            if (p < L) {
                int pi = p / WS, pj = p - pi * WS;
                float* dst = yb + (size_t)(o0 + 4 * lg) * NPIX
                               + (size_t)(h0 + pi) * IMG + (w0 + pj);
#pragma unroll
                for (int r = 0; r < 4; ++r)
                    dst[(size_t)r * NPIX] = acc[t][r];
            }
        }
    }
}

extern "C" void kernel_launch(void* const* d_in, const int* in_sizes, int n_in,
                              void* d_out, int out_size, void* d_ws, size_t ws_size,
                              hipStream_t stream) {
    (void)in_sizes; (void)n_in; (void)out_size; (void)ws_size;
    const float* x     = (const float*)d_in[0];
    const float* w_qkv = (const float*)d_in[1];
    const float* b_qkv = (const float*)d_in[2];
    const float* w_out = (const float*)d_in[3];
    const float* b_out = (const float*)d_in[4];
    float* y = (float*)d_out;
    short* wbf = (short*)d_ws;                 // 65536 bf16 = 131072 B

    cvt_weights<<<256, 256, 0, stream>>>(w_qkv, w_out, wbf);
    emsa_mfma<<<4096, TPB, 0, stream>>>(x, wbf, wbf + 384 * CCH,
                                        b_qkv, b_out, y);
}